// Round 2
// baseline (1526.057 us; speedup 1.0000x reference)
//
#include <hip/hip_runtime.h>

// ---------------- types / helpers ----------------
typedef __bf16 bf16;
typedef __attribute__((ext_vector_type(8))) __bf16 bf16x8;
typedef __attribute__((ext_vector_type(4))) float f32x4;

#define AS1U(p) ((const __attribute__((address_space(1))) unsigned int*)(p))
#define AS3U(p) ((__attribute__((address_space(3))) unsigned int*)(p))

__device__ __forceinline__ unsigned short f2bf(float f) {
    union { float f; unsigned int u; } a; a.f = f;
    unsigned int u = a.u;
    u += 0x7fffu + ((u >> 16) & 1u);   // round-to-nearest-even
    return (unsigned short)(u >> 16);
}
__device__ __forceinline__ unsigned int pk2(float a, float b) {
    return (unsigned int)f2bf(a) | ((unsigned int)f2bf(b) << 16);
}

// Problem constants
#define MTOT 32768            // B*H*W = 8*64*64
#define DIM  768
#define KP   832              // augmented K: 768 + 16 (mid_q) + 16 (mid_v) + 32 pad
#define NOUT 2304

// ---------------- kernel 0: build Bt [NOUT][KP] bf16 + WaT [32][768] bf16 ----------------
__global__ __launch_bounds__(256) void bbuild_kernel(
    const float* __restrict__ Wqkv, const float* __restrict__ Wbq,
    const float* __restrict__ Wbv, const float* __restrict__ Waq,
    const float* __restrict__ Wav, unsigned short* __restrict__ Bt,
    unsigned short* __restrict__ WaT)
{
    const int bx = blockIdx.x;
    const int t = threadIdx.x;
    if (bx < 432) {
        // transpose: kt-tile (12) x nt-tile (36), 64x64 fp32 via LDS
        __shared__ float Ts[64][65];
        const int kt = bx % 12, nt = bx / 12;
        #pragma unroll
        for (int it = 0; it < 4; ++it) {
            int idx = it * 256 + t;          // 0..1023
            int kr = idx >> 4;               // 0..63
            int nc = (idx & 15) * 4;         // 0..60
            float4 v = *(const float4*)(Wqkv + (size_t)(kt * 64 + kr) * NOUT + nt * 64 + nc);
            Ts[kr][nc + 0] = v.x; Ts[kr][nc + 1] = v.y;
            Ts[kr][nc + 2] = v.z; Ts[kr][nc + 3] = v.w;
        }
        __syncthreads();
        #pragma unroll
        for (int it = 0; it < 4; ++it) {
            int idx = it * 256 + t;
            int nr = idx >> 4;               // 0..63
            int kc = (idx & 15) * 4;         // 0..60
            ushort4 u;
            u.x = f2bf(Ts[kc + 0][nr]); u.y = f2bf(Ts[kc + 1][nr]);
            u.z = f2bf(Ts[kc + 2][nr]); u.w = f2bf(Ts[kc + 3][nr]);
            *(ushort4*)(Bt + (size_t)(nt * 64 + nr) * KP + kt * 64 + kc) = u;
        }
    } else if (bx < 576) {
        int idx = (bx - 432) * 256 + t;      // 0..36863
        int n = idx >> 4;                    // 0..2303
        int k = 768 + (idx & 15) * 4;
        ushort4 u;
        unsigned short* up = (unsigned short*)&u;
        #pragma unroll
        for (int j = 0; j < 4; ++j) {
            int kk = k + j;
            float v = 0.f;
            if (kk < 784) { if (n < 768) v = Wbq[(size_t)(kk - 768) * 768 + n]; }
            else if (kk < 800) { if (n >= 1536) v = Wbv[(size_t)(kk - 784) * 768 + (n - 1536)]; }
            up[j] = f2bf(v);
        }
        *(ushort4*)(Bt + (size_t)n * KP + k) = u;
    } else {
        int idx = (bx - 576) * 256 + t;      // 0..24575
        int n = idx / 768, k = idx % 768;
        float v = (n < 16) ? Waq[(size_t)k * 16 + n] : Wav[(size_t)k * 16 + (n - 16)];
        WaT[(size_t)n * 768 + k] = f2bf(v);
    }
}

// ---------------- kernel 1: x -> bf16 A'[:,0:768] + MFMA down-proj a_q/a_v ----------------
__global__ __launch_bounds__(256) void prep_kernel(
    const float* __restrict__ x, const bf16* __restrict__ WaT,
    unsigned short* __restrict__ Ap, float* __restrict__ aq, float* __restrict__ av)
{
    __shared__ bf16 Xs[64 * 64];
    const int t = threadIdx.x;
    const int wave = t >> 6, lane = t & 63;
    const int l15 = lane & 15, q = lane >> 4;
    const int p0 = blockIdx.x * 64;
    const int row = t >> 2, c16 = (t & 3) * 16;
    const int r8 = row & 7, ch0 = c16 >> 3;
    f32x4 acc[2] = {};

    for (int kt = 0; kt < 12; ++kt) {
        const float* xp = x + (size_t)(p0 + row) * DIM + kt * 64 + c16;
        float4 v0 = *(const float4*)(xp + 0);
        float4 v1 = *(const float4*)(xp + 4);
        float4 v2 = *(const float4*)(xp + 8);
        float4 v3 = *(const float4*)(xp + 12);
        uint4 u0, u1;
        u0.x = pk2(v0.x, v0.y); u0.y = pk2(v0.z, v0.w);
        u0.z = pk2(v1.x, v1.y); u0.w = pk2(v1.z, v1.w);
        u1.x = pk2(v2.x, v2.y); u1.y = pk2(v2.z, v2.w);
        u1.z = pk2(v3.x, v3.y); u1.w = pk2(v3.z, v3.w);
        // global A' (bf16)
        unsigned short* apq = Ap + (size_t)(p0 + row) * KP + kt * 64 + c16;
        *(uint4*)(apq) = u0;
        *(uint4*)(apq + 8) = u1;
        __syncthreads();                       // prev iter's LDS reads done
        // LDS, XOR-swizzled: chunk ch at phys slot ch^(row&7)
        *(uint4*)(Xs + row * 64 + ((ch0 + 0) ^ r8) * 8) = u0;
        *(uint4*)(Xs + row * 64 + ((ch0 + 1) ^ r8) * 8) = u1;
        __syncthreads();
        // B-frags from WaT (wave-shared, L1/L2-hot)
        bf16x8 bfr[2][2];
        #pragma unroll
        for (int kk = 0; kk < 2; ++kk)
            #pragma unroll
            for (int nf = 0; nf < 2; ++nf)
                bfr[kk][nf] = *(const bf16x8*)(WaT + (size_t)(nf * 16 + l15) * 768
                                               + kt * 64 + kk * 32 + q * 8);
        #pragma unroll
        for (int kk = 0; kk < 2; ++kk) {
            int phys = ((kk << 2) + q) ^ (l15 & 7);
            bf16x8 af = *(const bf16x8*)(Xs + (wave * 16 + l15) * 64 + phys * 8);
            acc[0] = __builtin_amdgcn_mfma_f32_16x16x32_bf16(af, bfr[kk][0], acc[0], 0, 0, 0);
            acc[1] = __builtin_amdgcn_mfma_f32_16x16x32_bf16(af, bfr[kk][1], acc[1], 0, 0, 0);
        }
    }
    // write a_q / a_v: C/D layout col=lane&15, row=q*4+r
    const int m = wave * 16 + q * 4;
    #pragma unroll
    for (int r = 0; r < 4; ++r) {
        aq[(size_t)(p0 + m + r) * 16 + l15] = acc[0][r];
        av[(size_t)(p0 + m + r) * 16 + l15] = acc[1][r];
    }
    // zero-fill A' pad columns 800..831
    uint4 z; z.x = z.y = z.z = z.w = 0u;
    *(uint4*)(Ap + (size_t)(p0 + row) * KP + 800 + (t & 3) * 8) = z;
}

// ---------------- kernel 2: mid = conv3(a)+b3 + conv1(a)+b1 + a -> A'[:,768+qv*16] ----------------
__global__ __launch_bounds__(256) void conv_mid_kernel(
    const float* __restrict__ aq, const float* __restrict__ av,
    const float* __restrict__ Kq3, const float* __restrict__ bq3,
    const float* __restrict__ Kv3, const float* __restrict__ bv3,
    const float* __restrict__ Kq1, const float* __restrict__ bq1,
    const float* __restrict__ Kv1, const float* __restrict__ bv1,
    unsigned short* __restrict__ Ap)
{
    const int bx = blockIdx.x;
    const int qv   = bx & 1;
    const int tile = (bx >> 1) & 15;
    const int b    = bx >> 5;
    const float* a  = qv ? av  : aq;
    const float* K3 = qv ? Kv3 : Kq3;
    const float* K1 = qv ? Kv1 : Kq1;
    const float* b3 = qv ? bv3 : bq3;
    const float* b1 = qv ? bv1 : bq1;

    __shared__ float K3s[9][16][16];
    __shared__ float K1s[16][16];
    const int t = threadIdx.x;
    for (int i = t; i < 9 * 256; i += 256) ((float*)K3s)[i] = K3[i];
    ((float*)K1s)[t] = K1[t];
    __syncthreads();

    const int lh = t >> 4, lw = t & 15;
    const int h = (tile >> 2) * 16 + lh;
    const int w = (tile & 3) * 16 + lw;

    float acc[16];
    const float* ac = a + (((size_t)b * 64 + h) * 64 + w) * 16;
    float cen[16];
    #pragma unroll
    for (int i4 = 0; i4 < 4; ++i4) {
        float4 qd = ((const float4*)ac)[i4];
        cen[i4 * 4 + 0] = qd.x; cen[i4 * 4 + 1] = qd.y;
        cen[i4 * 4 + 2] = qd.z; cen[i4 * 4 + 3] = qd.w;
    }
    #pragma unroll
    for (int o = 0; o < 16; ++o) acc[o] = b3[o] + b1[o] + cen[o];
    #pragma unroll
    for (int i = 0; i < 16; ++i) {
        float vi = cen[i];
        #pragma unroll
        for (int o = 0; o < 16; ++o) acc[o] += vi * K1s[i][o];
    }
    for (int dh = -1; dh <= 1; ++dh) {
        for (int dw = -1; dw <= 1; ++dw) {
            int hh = h + dh, ww = w + dw;
            if ((unsigned)hh < 64u && (unsigned)ww < 64u) {
                const float* ap = a + (((size_t)b * 64 + hh) * 64 + ww) * 16;
                float v[16];
                #pragma unroll
                for (int i4 = 0; i4 < 4; ++i4) {
                    float4 qd = ((const float4*)ap)[i4];
                    v[i4 * 4 + 0] = qd.x; v[i4 * 4 + 1] = qd.y;
                    v[i4 * 4 + 2] = qd.z; v[i4 * 4 + 3] = qd.w;
                }
                const int tap = (dh + 1) * 3 + (dw + 1);
                #pragma unroll
                for (int i = 0; i < 16; ++i) {
                    float vi = v[i];
                    #pragma unroll
                    for (int o = 0; o < 16; ++o) acc[o] += vi * K3s[tap][i][o];
                }
            }
        }
    }
    unsigned short* dst = Ap + (((size_t)b * 64 + h) * 64 + w) * KP + 768 + qv * 16;
    #pragma unroll
    for (int o4 = 0; o4 < 4; ++o4) {
        ushort4 u;
        u.x = f2bf(acc[o4 * 4 + 0]); u.y = f2bf(acc[o4 * 4 + 1]);
        u.z = f2bf(acc[o4 * 4 + 2]); u.w = f2bf(acc[o4 * 4 + 3]);
        *(ushort4*)(dst + o4 * 4) = u;
    }
}

// ---------------- kernel 3: GEMM out[M,N] = A'[M,KP] * Bt[N,KP]^T + b_qkv ----------------
// 256x256 tile, BK=64, 8 waves as 4M x 2N (wave: 64 rows x 128 cols).
// A: global_load_lds into 2x32KB dbuf (64 KB LDS -> 2 blocks/CU), XOR chunk
// swizzle folded into the global address. B: DIRECT global->VGPR loads from
// L1/L2-resident Bt (no LDS round-trip; 4 waves share each N-panel).
// Counted vmcnt: at tile top issue B(kt) [16 loads] + STAGE(kt+1) [4 loads],
// then vmcnt(20) retires exactly stage(kt) -- B(kt)+stage(kt+1) stay in
// flight; compiler inserts its own waits for the B reg-loads before use.
// XCD-chunked bijective swizzle (1152 = 8*144): each XCD owns 16 contiguous
// M-rows, N-fastest within, so A-panels stay XCD-L2/L3-resident.
__global__ __launch_bounds__(512, 4) void gemm_kernel(
    const bf16* __restrict__ A, const bf16* __restrict__ Bt,
    const float* __restrict__ bias, float* __restrict__ out)
{
    __shared__ bf16 As[2][256 * 64];          // 64 KB total
    const int t = threadIdx.x;                // 0..511
    const int wave = t >> 6, lane = t & 63;
    const int wm = wave & 3, wn = wave >> 2;  // 4M x 2N wave grid

    // XCD-chunked swizzle: hw block i lands on XCD i%8; give XCD its own M-chunk
    const int bid = blockIdx.x;               // 0..1151
    const int xcd = bid & 7, w = bid >> 3;    // w in [0,144)
    const int mb = xcd * 16 + w / 9, nb = w % 9;
    const int m0 = mb * 256, n0 = nb * 256;

    // A staging geometry: per K-tile each thread issues 4 loads (16 B each)
    const int sr8 = lane >> 3;                // row within 8-row group
    const int slc = (lane & 7) ^ sr8;         // pre-swizzled logical k-chunk
    const bf16* gA = A + (size_t)(m0 + wave * 8 + sr8) * KP + slc * 8;
    const int ldsbase = wave * 512 + lane * 8;

    const int l15 = lane & 15, q = lane >> 4, l7 = lane & 7;

    f32x4 acc[4][8] = {};

    auto STAGE = [&](int kt1, int bufi) {
        const int k0 = kt1 * 64;
        #pragma unroll
        for (int it = 0; it < 4; ++it)
            __builtin_amdgcn_global_load_lds(AS1U(gA + (size_t)(it * 64) * KP + k0),
                AS3U(&As[bufi][it * 4096 + ldsbase]), 16, 0, 0);
    };

    // B-frag base: lane reads row n0+wn*128+ni*16+l15, k-slot q
    const bf16* gBw = Bt + (size_t)(n0 + wn * 128 + l15) * KP + q * 8;

    STAGE(0, 0);                              // prologue: tile 0 A in flight

    for (int kt = 0; kt < 13; ++kt) {
        const int cur = kt & 1;
        // B fragments for tile kt: 16 global 16B loads, L1/L2-hot, reg-resident
        bf16x8 bfr[2][8];
        #pragma unroll
        for (int ni = 0; ni < 8; ++ni)
            #pragma unroll
            for (int kk = 0; kk < 2; ++kk)
                bfr[kk][ni] = *(const bf16x8*)(gBw + (size_t)(ni * 16) * KP
                                               + kt * 64 + kk * 32);
        if (kt < 12) {
            STAGE(kt + 1, cur ^ 1);           // prefetch next A tile
            // outstanding: stage(kt)=4 oldest, B(kt)=16, stage(kt+1)=4 -> 24
            asm volatile("s_waitcnt vmcnt(20)\n\ts_barrier" ::: "memory");
        } else {
            // outstanding: stage(12)=4 oldest, B(12)=16 -> 20
            asm volatile("s_waitcnt vmcnt(16)\n\ts_barrier" ::: "memory");
        }

        const bf16* as = &As[cur][0];
        #pragma unroll
        for (int p = 0; p < 4; ++p) {
            // A-frags for mi=p (2 ds_read_b128), un-swizzle on read
            bf16x8 af[2];
            #pragma unroll
            for (int kk = 0; kk < 2; ++kk) {
                const int phys = ((kk << 2) + q) ^ l7;
                af[kk] = *(const bf16x8*)(as + (wm * 64 + p * 16 + l15) * 64 + phys * 8);
            }
            __builtin_amdgcn_s_setprio(1);
            #pragma unroll
            for (int ni = 0; ni < 8; ++ni)
                #pragma unroll
                for (int kk = 0; kk < 2; ++kk)
                    acc[p][ni] = __builtin_amdgcn_mfma_f32_16x16x32_bf16(
                        af[kk], bfr[kk][ni], acc[p][ni], 0, 0, 0);
            __builtin_amdgcn_s_setprio(0);
            if (p < 3) __builtin_amdgcn_s_barrier();   // phase pacing
        }
        // all waves done reading As[cur] before next tile's STAGE overwrites peer buf
        asm volatile("s_barrier" ::: "memory");
    }

    // epilogue: C/D layout col=lane&15, row=(lane>>4)*4+reg
    #pragma unroll
    for (int ni = 0; ni < 8; ++ni) {
        const int col = n0 + wn * 128 + ni * 16 + l15;
        const float bv = bias[col];
        #pragma unroll
        for (int mi = 0; mi < 4; ++mi) {
            const int rbase = m0 + wm * 64 + mi * 16 + (q << 2);
            #pragma unroll
            for (int r = 0; r < 4; ++r)
                out[(size_t)(rbase + r) * NOUT + col] = acc[mi][ni][r] + bv;
        }
    }
}

// ---------------- launch ----------------
extern "C" void kernel_launch(void* const* d_in, const int* in_sizes, int n_in,
                              void* d_out, int out_size, void* d_ws, size_t ws_size,
                              hipStream_t stream) {
    const float* x    = (const float*)d_in[0];
    const float* Wqkv = (const float*)d_in[1];
    const float* bqkv = (const float*)d_in[2];
    const float* Waq  = (const float*)d_in[3];
    const float* Wbq  = (const float*)d_in[4];
    const float* Wav  = (const float*)d_in[5];
    const float* Wbv  = (const float*)d_in[6];
    const float* Kq3  = (const float*)d_in[7];
    const float* bq3  = (const float*)d_in[8];
    const float* Kv3  = (const float*)d_in[9];
    const float* bv3  = (const float*)d_in[10];
    const float* Kq1  = (const float*)d_in[11];
    const float* bq1  = (const float*)d_in[12];
    const float* Kv1  = (const float*)d_in[13];
    const float* bv1  = (const float*)d_in[14];
    float* out = (float*)d_out;

    // workspace layout (total 62,603,264 B)
    char* ws = (char*)d_ws;
    unsigned short* Ap  = (unsigned short*)ws;                        // [32768][832] bf16
    float* aq           = (float*)(ws + 54525952);                    // [32768][16] fp32
    float* av           = (float*)(ws + 54525952 + 2097152);          // [32768][16] fp32
    unsigned short* Bt  = (unsigned short*)(ws + 54525952 + 4194304); // [2304][832] bf16
    unsigned short* WaT = (unsigned short*)(ws + 62554112);           // [32][768] bf16

    bbuild_kernel<<<672, 256, 0, stream>>>(Wqkv, Wbq, Wbv, Waq, Wav, Bt, WaT);
    prep_kernel<<<MTOT / 64, 256, 0, stream>>>(x, (const bf16*)WaT, Ap, aq, av);
    conv_mid_kernel<<<256, 256, 0, stream>>>(aq, av, Kq3, bq3, Kv3, bv3,
                                             Kq1, bq1, Kv1, bv1, Ap);
    gemm_kernel<<<1152, 512, 0, stream>>>(
        (const bf16*)Ap, (const bf16*)Bt, bqkv, out);
}

// Round 3
// 540.824 us; speedup vs baseline: 2.8217x; 2.8217x over previous
//
#include <hip/hip_runtime.h>

// ---------------- types / helpers ----------------
typedef __bf16 bf16;
typedef __attribute__((ext_vector_type(8))) __bf16 bf16x8;
typedef __attribute__((ext_vector_type(4))) float f32x4;

#define AS1U(p) ((const __attribute__((address_space(1))) unsigned int*)(p))
#define AS3U(p) ((__attribute__((address_space(3))) unsigned int*)(p))

__device__ __forceinline__ unsigned short f2bf(float f) {
    union { float f; unsigned int u; } a; a.f = f;
    unsigned int u = a.u;
    u += 0x7fffu + ((u >> 16) & 1u);   // round-to-nearest-even
    return (unsigned short)(u >> 16);
}
__device__ __forceinline__ unsigned int pk2(float a, float b) {
    return (unsigned int)f2bf(a) | ((unsigned int)f2bf(b) << 16);
}

// Problem constants
#define MTOT 32768            // B*H*W = 8*64*64
#define DIM  768
#define KP   832              // augmented K: 768 + 16 (mid_q) + 16 (mid_v) + 32 pad
#define NOUT 2304

// ---------------- kernel 0: build Bt [NOUT][KP] bf16 + WaT [32][768] bf16 ----------------
__global__ __launch_bounds__(256) void bbuild_kernel(
    const float* __restrict__ Wqkv, const float* __restrict__ Wbq,
    const float* __restrict__ Wbv, const float* __restrict__ Waq,
    const float* __restrict__ Wav, unsigned short* __restrict__ Bt,
    unsigned short* __restrict__ WaT)
{
    const int bx = blockIdx.x;
    const int t = threadIdx.x;
    if (bx < 432) {
        // transpose: kt-tile (12) x nt-tile (36), 64x64 fp32 via LDS
        __shared__ float Ts[64][65];
        const int kt = bx % 12, nt = bx / 12;
        #pragma unroll
        for (int it = 0; it < 4; ++it) {
            int idx = it * 256 + t;          // 0..1023
            int kr = idx >> 4;               // 0..63
            int nc = (idx & 15) * 4;         // 0..60
            float4 v = *(const float4*)(Wqkv + (size_t)(kt * 64 + kr) * NOUT + nt * 64 + nc);
            Ts[kr][nc + 0] = v.x; Ts[kr][nc + 1] = v.y;
            Ts[kr][nc + 2] = v.z; Ts[kr][nc + 3] = v.w;
        }
        __syncthreads();
        #pragma unroll
        for (int it = 0; it < 4; ++it) {
            int idx = it * 256 + t;
            int nr = idx >> 4;               // 0..63
            int kc = (idx & 15) * 4;         // 0..60
            ushort4 u;
            u.x = f2bf(Ts[kc + 0][nr]); u.y = f2bf(Ts[kc + 1][nr]);
            u.z = f2bf(Ts[kc + 2][nr]); u.w = f2bf(Ts[kc + 3][nr]);
            *(ushort4*)(Bt + (size_t)(nt * 64 + nr) * KP + kt * 64 + kc) = u;
        }
    } else if (bx < 576) {
        int idx = (bx - 432) * 256 + t;      // 0..36863
        int n = idx >> 4;                    // 0..2303
        int k = 768 + (idx & 15) * 4;
        ushort4 u;
        unsigned short* up = (unsigned short*)&u;
        #pragma unroll
        for (int j = 0; j < 4; ++j) {
            int kk = k + j;
            float v = 0.f;
            if (kk < 784) { if (n < 768) v = Wbq[(size_t)(kk - 768) * 768 + n]; }
            else if (kk < 800) { if (n >= 1536) v = Wbv[(size_t)(kk - 784) * 768 + (n - 1536)]; }
            up[j] = f2bf(v);
        }
        *(ushort4*)(Bt + (size_t)n * KP + k) = u;
    } else {
        int idx = (bx - 576) * 256 + t;      // 0..24575
        int n = idx / 768, k = idx % 768;
        float v = (n < 16) ? Waq[(size_t)k * 16 + n] : Wav[(size_t)k * 16 + (n - 16)];
        WaT[(size_t)n * 768 + k] = f2bf(v);
    }
}

// ---------------- kernel 1: x -> bf16 A'[:,0:768] + MFMA down-proj a_q/a_v ----------------
// LDS-free / barrier-free: the wave's coalesced x load covers exactly the
// 16 rows x 64 ch its MFMA fragments need, so A-frags re-read x directly
// (L1-hot) with per-lane fp32->bf16 convert (bit-identical to staging path).
// Compiler can software-pipeline all 12 K-steps (no syncthreads).
__global__ __launch_bounds__(256) void prep_kernel(
    const float* __restrict__ x, const bf16* __restrict__ WaT,
    unsigned short* __restrict__ Ap, float* __restrict__ aq, float* __restrict__ av)
{
    const int t = threadIdx.x;
    const int wave = t >> 6, lane = t & 63;
    const int l15 = lane & 15, q = lane >> 4;
    const int p0 = blockIdx.x * 64;
    const int row = t >> 2, c16 = (t & 3) * 16;
    f32x4 acc[2] = {};

    for (int kt = 0; kt < 12; ++kt) {
        // coalesced: thread covers row (t>>2), 16 ch of the kt-block
        const float* xp = x + (size_t)(p0 + row) * DIM + kt * 64 + c16;
        float4 v0 = *(const float4*)(xp + 0);
        float4 v1 = *(const float4*)(xp + 4);
        float4 v2 = *(const float4*)(xp + 8);
        float4 v3 = *(const float4*)(xp + 12);
        uint4 u0, u1;
        u0.x = pk2(v0.x, v0.y); u0.y = pk2(v0.z, v0.w);
        u0.z = pk2(v1.x, v1.y); u0.w = pk2(v1.z, v1.w);
        u1.x = pk2(v2.x, v2.y); u1.y = pk2(v2.z, v2.w);
        u1.z = pk2(v3.x, v3.y); u1.w = pk2(v3.z, v3.w);
        // global A' (bf16)
        unsigned short* apq = Ap + (size_t)(p0 + row) * KP + kt * 64 + c16;
        *(uint4*)(apq) = u0;
        *(uint4*)(apq + 8) = u1;
        // B-frags from WaT (wave-shared, L1/L2-hot)
        bf16x8 bfr[2][2];
        #pragma unroll
        for (int kk = 0; kk < 2; ++kk)
            #pragma unroll
            for (int nf = 0; nf < 2; ++nf)
                bfr[kk][nf] = *(const bf16x8*)(WaT + (size_t)(nf * 16 + l15) * 768
                                               + kt * 64 + kk * 32 + q * 8);
        // A-frags direct from x (L1-hot; same lines the wave just fetched)
        #pragma unroll
        for (int kk = 0; kk < 2; ++kk) {
            const float* fp = x + (size_t)(p0 + wave * 16 + l15) * DIM
                              + kt * 64 + kk * 32 + q * 8;
            float4 a0 = *(const float4*)(fp + 0);
            float4 a1 = *(const float4*)(fp + 4);
            union { uint4 u; bf16x8 v; } ua;
            ua.u.x = pk2(a0.x, a0.y); ua.u.y = pk2(a0.z, a0.w);
            ua.u.z = pk2(a1.x, a1.y); ua.u.w = pk2(a1.z, a1.w);
            acc[0] = __builtin_amdgcn_mfma_f32_16x16x32_bf16(ua.v, bfr[kk][0], acc[0], 0, 0, 0);
            acc[1] = __builtin_amdgcn_mfma_f32_16x16x32_bf16(ua.v, bfr[kk][1], acc[1], 0, 0, 0);
        }
    }
    // write a_q / a_v: C/D layout col=lane&15, row=q*4+r
    const int m = wave * 16 + q * 4;
    #pragma unroll
    for (int r = 0; r < 4; ++r) {
        aq[(size_t)(p0 + m + r) * 16 + l15] = acc[0][r];
        av[(size_t)(p0 + m + r) * 16 + l15] = acc[1][r];
    }
    // zero-fill A' pad columns 800..831
    uint4 z; z.x = z.y = z.z = z.w = 0u;
    *(uint4*)(Ap + (size_t)(p0 + row) * KP + 800 + (t & 3) * 8) = z;
}

// ---------------- kernel 2: mid = conv3(a)+b3 + conv1(a)+b1 + a -> A'[:,768+qv*16] ----------------
__global__ __launch_bounds__(256) void conv_mid_kernel(
    const float* __restrict__ aq, const float* __restrict__ av,
    const float* __restrict__ Kq3, const float* __restrict__ bq3,
    const float* __restrict__ Kv3, const float* __restrict__ bv3,
    const float* __restrict__ Kq1, const float* __restrict__ bq1,
    const float* __restrict__ Kv1, const float* __restrict__ bv1,
    unsigned short* __restrict__ Ap)
{
    const int bx = blockIdx.x;
    const int qv   = bx & 1;
    const int tile = (bx >> 1) & 15;
    const int b    = bx >> 5;
    const float* a  = qv ? av  : aq;
    const float* K3 = qv ? Kv3 : Kq3;
    const float* K1 = qv ? Kv1 : Kq1;
    const float* b3 = qv ? bv3 : bq3;
    const float* b1 = qv ? bv1 : bq1;

    __shared__ float K3s[9][16][16];
    __shared__ float K1s[16][16];
    const int t = threadIdx.x;
    for (int i = t; i < 9 * 256; i += 256) ((float*)K3s)[i] = K3[i];
    ((float*)K1s)[t] = K1[t];
    __syncthreads();

    const int lh = t >> 4, lw = t & 15;
    const int h = (tile >> 2) * 16 + lh;
    const int w = (tile & 3) * 16 + lw;

    float acc[16];
    const float* ac = a + (((size_t)b * 64 + h) * 64 + w) * 16;
    float cen[16];
    #pragma unroll
    for (int i4 = 0; i4 < 4; ++i4) {
        float4 qd = ((const float4*)ac)[i4];
        cen[i4 * 4 + 0] = qd.x; cen[i4 * 4 + 1] = qd.y;
        cen[i4 * 4 + 2] = qd.z; cen[i4 * 4 + 3] = qd.w;
    }
    #pragma unroll
    for (int o = 0; o < 16; ++o) acc[o] = b3[o] + b1[o] + cen[o];
    #pragma unroll
    for (int i = 0; i < 16; ++i) {
        float vi = cen[i];
        #pragma unroll
        for (int o = 0; o < 16; ++o) acc[o] += vi * K1s[i][o];
    }
    for (int dh = -1; dh <= 1; ++dh) {
        for (int dw = -1; dw <= 1; ++dw) {
            int hh = h + dh, ww = w + dw;
            if ((unsigned)hh < 64u && (unsigned)ww < 64u) {
                const float* ap = a + (((size_t)b * 64 + hh) * 64 + ww) * 16;
                float v[16];
                #pragma unroll
                for (int i4 = 0; i4 < 4; ++i4) {
                    float4 qd = ((const float4*)ap)[i4];
                    v[i4 * 4 + 0] = qd.x; v[i4 * 4 + 1] = qd.y;
                    v[i4 * 4 + 2] = qd.z; v[i4 * 4 + 3] = qd.w;
                }
                const int tap = (dh + 1) * 3 + (dw + 1);
                #pragma unroll
                for (int i = 0; i < 16; ++i) {
                    float vi = v[i];
                    #pragma unroll
                    for (int o = 0; o < 16; ++o) acc[o] += vi * K3s[tap][i][o];
                }
            }
        }
    }
    unsigned short* dst = Ap + (((size_t)b * 64 + h) * 64 + w) * KP + 768 + qv * 16;
    #pragma unroll
    for (int o4 = 0; o4 < 4; ++o4) {
        ushort4 u;
        u.x = f2bf(acc[o4 * 4 + 0]); u.y = f2bf(acc[o4 * 4 + 1]);
        u.z = f2bf(acc[o4 * 4 + 2]); u.w = f2bf(acc[o4 * 4 + 3]);
        *(ushort4*)(dst + o4 * 4) = u;
    }
}

// ---------------- kernel 3: GEMM out[M,N] = A'[M,KP] * Bt[N,KP]^T + b_qkv ----------------
// 128x128 tile, BK=64, 4 waves 2x2, each 4x4 of 16x16x32 bf16 MFMA.
// global_load_lds width-16 with XOR chunk-swizzle folded into the global address.
// Chunked-XCD block remap (bijective, 4608 = 8*576): each XCD owns 32
// contiguous M-tiles x all 18 N-tiles -> A-panel + whole B stay L2-resident.
__global__ __launch_bounds__(256, 2) void gemm_kernel(
    const bf16* __restrict__ A, const bf16* __restrict__ Bt,
    const float* __restrict__ bias, float* __restrict__ out)
{
    __shared__ bf16 As[128 * 64];
    __shared__ bf16 Bs[128 * 64];
    const int t = threadIdx.x;
    const int wave = t >> 6, lane = t & 63;
    // chunked XCD remap: hw round-robins blockIdx.x % 8 across XCDs
    const int lb = blockIdx.x;               // 0..4607
    const int xcd = lb & 7, c = lb >> 3;     // c in [0,576)
    const int g = xcd * 576 + c;             // contiguous per-XCD chunk
    const int m0 = (g / 18) * 128, n0 = (g % 18) * 128;
    const int wm = wave & 1, wn = wave >> 1;

    f32x4 acc[4][4] = {};

    const int sr = lane >> 3;                 // row within 8-row chunk
    const int ql = (lane & 7) ^ sr;           // logical k-chunk this lane fetches (swizzle)

    for (int kt = 0; kt < 13; ++kt) {
        const int k0 = kt * 64;
        __syncthreads();
        #pragma unroll
        for (int it = 0; it < 4; ++it) {
            int ci = wave * 4 + it;           // 16 chunks of 8 rows
            int r = ci * 8 + sr;
            const bf16* ga = A  + (size_t)(m0 + r) * KP + k0 + ql * 8;
            __builtin_amdgcn_global_load_lds(AS1U(ga), AS3U(As + ci * 512 + lane * 8), 16, 0, 0);
            const bf16* gb = Bt + (size_t)(n0 + r) * KP + k0 + ql * 8;
            __builtin_amdgcn_global_load_lds(AS1U(gb), AS3U(Bs + ci * 512 + lane * 8), 16, 0, 0);
        }
        __syncthreads();
        #pragma unroll
        for (int kk = 0; kk < 2; ++kk) {
            bf16x8 af[4], bfr[4];
            const int phys = ((kk << 2) + (lane >> 4)) ^ (lane & 7);  // un-swizzle
            #pragma unroll
            for (int mi = 0; mi < 4; ++mi) {
                int rr = wm * 64 + mi * 16 + (lane & 15);
                af[mi] = *(const bf16x8*)(As + rr * 64 + phys * 8);
            }
            #pragma unroll
            for (int ni = 0; ni < 4; ++ni) {
                int rr = wn * 64 + ni * 16 + (lane & 15);
                bfr[ni] = *(const bf16x8*)(Bs + rr * 64 + phys * 8);
            }
            #pragma unroll
            for (int mi = 0; mi < 4; ++mi)
                #pragma unroll
                for (int ni = 0; ni < 4; ++ni)
                    acc[mi][ni] = __builtin_amdgcn_mfma_f32_16x16x32_bf16(
                        af[mi], bfr[ni], acc[mi][ni], 0, 0, 0);
        }
    }
    // epilogue: C/D layout col=lane&15, row=(lane>>4)*4+reg
    #pragma unroll
    for (int ni = 0; ni < 4; ++ni) {
        int col = n0 + wn * 64 + ni * 16 + (lane & 15);
        float bv = bias[col];
        #pragma unroll
        for (int mi = 0; mi < 4; ++mi) {
            int rbase = m0 + wm * 64 + mi * 16 + ((lane >> 4) << 2);
            #pragma unroll
            for (int r = 0; r < 4; ++r)
                out[(size_t)(rbase + r) * NOUT + col] = acc[mi][ni][r] + bv;
        }
    }
}

// ---------------- launch ----------------
extern "C" void kernel_launch(void* const* d_in, const int* in_sizes, int n_in,
                              void* d_out, int out_size, void* d_ws, size_t ws_size,
                              hipStream_t stream) {
    const float* x    = (const float*)d_in[0];
    const float* Wqkv = (const float*)d_in[1];
    const float* bqkv = (const float*)d_in[2];
    const float* Waq  = (const float*)d_in[3];
    const float* Wbq  = (const float*)d_in[4];
    const float* Wav  = (const float*)d_in[5];
    const float* Wbv  = (const float*)d_in[6];
    const float* Kq3  = (const float*)d_in[7];
    const float* bq3  = (const float*)d_in[8];
    const float* Kv3  = (const float*)d_in[9];
    const float* bv3  = (const float*)d_in[10];
    const float* Kq1  = (const float*)d_in[11];
    const float* bq1  = (const float*)d_in[12];
    const float* Kv1  = (const float*)d_in[13];
    const float* bv1  = (const float*)d_in[14];
    float* out = (float*)d_out;

    // workspace layout (total 62,603,264 B)
    char* ws = (char*)d_ws;
    unsigned short* Ap  = (unsigned short*)ws;                        // [32768][832] bf16
    float* aq           = (float*)(ws + 54525952);                    // [32768][16] fp32
    float* av           = (float*)(ws + 54525952 + 2097152);          // [32768][16] fp32
    unsigned short* Bt  = (unsigned short*)(ws + 54525952 + 4194304); // [2304][832] bf16
    unsigned short* WaT = (unsigned short*)(ws + 62554112);           // [32][768] bf16

    bbuild_kernel<<<672, 256, 0, stream>>>(Wqkv, Wbq, Wbv, Waq, Wav, Bt, WaT);
    prep_kernel<<<MTOT / 64, 256, 0, stream>>>(x, (const bf16*)WaT, Ap, aq, av);
    conv_mid_kernel<<<256, 256, 0, stream>>>(aq, av, Kq3, bq3, Kv3, bv3,
                                             Kq1, bq1, Kv1, bv1, Ap);
    gemm_kernel<<<4608, 256, 0, stream>>>(
        (const bf16*)Ap, (const bf16*)Bt, bqkv, out);
}